// Round 4
// baseline (292.859 us; speedup 1.0000x reference)
//
#include <hip/hip_runtime.h>
#include <math.h>

#define BINS 10
#define HSTRIDE 11                 // 10 bins padded to 11: (tid*11+b)%32 -> 2-way/wave = free
#define K1_THREADS 256
#define K1_MAXBLOCKS 1792          // 7 blocks/CU * 256 CU
#define HOFF (K1_THREADS * HSTRIDE)   // float offset of the sum array (11264 B, fits ds imm)

// Per-element: xs = label ? -x : x ; p_norm = sigmoid(xs) ; bce = softplus(xs).
// Histogram update: two fire-and-forget ds_add_f32 into this THREAD's private
// LDS rows (no sharing -> no contention; non-returning -> no dependency chain;
// runs on the LDS pipe concurrently with VALU).
__device__ __forceinline__ void ghm_elem(int y, float x, float w,
                                         float* __restrict__ hb) {
    float xs = (y == 1) ? -x : x;
    float e  = __expf(-fabsf(xs));              // exp(-|xs|) in (0,1]
    float d  = 1.0f + e;
    float r  = __builtin_amdgcn_rcpf(d);        // v_rcp_f32
    float pn = (xs >= 0.0f) ? r : e * r;        // sigmoid(xs) == p_norm
    int bin  = (int)(pn * 10.0f);               // pn>0 -> trunc == floor
    bin = bin > (BINS - 1) ? (BINS - 1) : bin;  // pn==1.0 edge (exp underflow)
    float bce = fmaxf(xs, 0.0f) + __logf(d);    // log(d) == log1p(e)
    bool  v   = (w > 0.0f);
    float cv  = v ? 1.0f : 0.0f;
    float sv  = v ? bce  : 0.0f;
    __hip_atomic_fetch_add(&hb[bin],        cv, __ATOMIC_RELAXED, __HIP_MEMORY_SCOPE_WORKGROUP);
    __hip_atomic_fetch_add(&hb[bin + HOFF], sv, __ATOMIC_RELAXED, __HIP_MEMORY_SCOPE_WORKGROUP);
}

// Kernel 1: per-block partial {count, sum(bce*valid)} per bin.
// partial layout in d_ws: rows 0..9 = counts, rows 10..19 = sums, nb cols.
__global__ __launch_bounds__(K1_THREADS) void ghm_partial(
    const int*   __restrict__ labels,
    const float* __restrict__ logits,
    const float* __restrict__ weights,
    float*       __restrict__ partial,
    int n8, int n, int nb)
{
    __shared__ float h[2 * HOFF];               // [copies=256][11] counts, then sums
    const int tid = threadIdx.x;

    #pragma unroll
    for (int i = tid; i < 2 * HOFF; i += K1_THREADS) h[i] = 0.0f;
    __syncthreads();

    float* hb = &h[tid * HSTRIDE];

    const int4*   lab4 = (const int4*)labels;
    const float4* log4 = (const float4*)logits;
    const float4* w4   = (const float4*)weights;

    const int stride = gridDim.x * blockDim.x;
    for (int i = blockIdx.x * blockDim.x + tid; i < n8; i += stride) {
        const int b0 = i * 2;
        int4   lb0 = lab4[b0],  lb1 = lab4[b0 + 1];
        float4 xv0 = log4[b0],  xv1 = log4[b0 + 1];
        float4 wv0 = w4[b0],    wv1 = w4[b0 + 1];

        ghm_elem(lb0.x, xv0.x, wv0.x, hb);
        ghm_elem(lb0.y, xv0.y, wv0.y, hb);
        ghm_elem(lb0.z, xv0.z, wv0.z, hb);
        ghm_elem(lb0.w, xv0.w, wv0.w, hb);
        ghm_elem(lb1.x, xv1.x, wv1.x, hb);
        ghm_elem(lb1.y, xv1.y, wv1.y, hb);
        ghm_elem(lb1.z, xv1.z, wv1.z, hb);
        ghm_elem(lb1.w, xv1.w, wv1.w, hb);
    }

    // scalar tail (n % 8), block 0 only (n divisible by 8 for this shape)
    const int rem_start = n8 * 8;
    if (blockIdx.x == 0 && tid < (n - rem_start)) {
        const int idx = rem_start + tid;
        ghm_elem(labels[idx], logits[idx], weights[idx], hb);
    }

    __syncthreads();

    // fold 256 private copies: regs <- own copy, wave shuffle, cross-wave via LDS
    float c[BINS], s[BINS];
    #pragma unroll
    for (int b = 0; b < BINS; ++b) {
        c[b] = h[tid * HSTRIDE + b];
        s[b] = h[HOFF + tid * HSTRIDE + b];
    }
    #pragma unroll
    for (int off = 32; off > 0; off >>= 1) {
        #pragma unroll
        for (int b = 0; b < BINS; ++b) {
            c[b] += __shfl_down(c[b], off);
            s[b] += __shfl_down(s[b], off);
        }
    }
    __syncthreads();                       // done reading h; safe to reuse
    const int wave = tid >> 6, lane = tid & 63;
    if (lane == 0) {
        #pragma unroll
        for (int b = 0; b < BINS; ++b) {
            h[wave * 2 * BINS + b]        = c[b];
            h[wave * 2 * BINS + BINS + b] = s[b];
        }
    }
    __syncthreads();
    if (tid < 2 * BINS) {
        float acc = 0.0f;
        #pragma unroll
        for (int wv = 0; wv < K1_THREADS / 64; ++wv)
            acc += h[wv * 2 * BINS + tid];
        partial[tid * nb + blockIdx.x] = acc;
    }
}

// Kernel 2: reduce nb partial columns, finalize scalar.
__global__ __launch_bounds__(1024) void ghm_final(
    const float* __restrict__ partial, float* __restrict__ out, int nb)
{
    const int tid = threadIdx.x;
    float acc[2 * BINS];
    #pragma unroll
    for (int b = 0; b < 2 * BINS; ++b) acc[b] = 0.0f;
    for (int j = tid; j < nb; j += 1024) {
        #pragma unroll
        for (int b = 0; b < 2 * BINS; ++b)
            acc[b] += partial[b * nb + j];     // coalesced row loads
    }

    #pragma unroll
    for (int off = 32; off > 0; off >>= 1) {
        #pragma unroll
        for (int b = 0; b < 2 * BINS; ++b)
            acc[b] += __shfl_down(acc[b], off);
    }

    __shared__ float red[16][2 * BINS];
    const int wave = tid >> 6, lane = tid & 63;
    if (lane == 0) {
        #pragma unroll
        for (int b = 0; b < 2 * BINS; ++b) red[wave][b] = acc[b];
    }
    __syncthreads();

    if (tid == 0) {
        float cnt[BINS], s[BINS];
        #pragma unroll
        for (int b = 0; b < BINS; ++b) { cnt[b] = 0.0f; s[b] = 0.0f; }
        for (int wv = 0; wv < 16; ++wv) {
            #pragma unroll
            for (int b = 0; b < BINS; ++b) {
                cnt[b] += red[wv][b];
                s[b]   += red[wv][BINS + b];
            }
        }
        float nn = 0.0f, res = 0.0f;
        #pragma unroll
        for (int b = 0; b < BINS; ++b) {
            if (cnt[b] > 0.0f) {
                nn  += 1.0f;
                res += s[b] / fmaxf(cnt[b], 1.0f);
            }
        }
        if (nn > 0.0f) res /= nn;   // total_num cancels exactly in the algebra
        out[0] = res;
    }
}

extern "C" void kernel_launch(void* const* d_in, const int* in_sizes, int n_in,
                              void* d_out, int out_size, void* d_ws, size_t ws_size,
                              hipStream_t stream) {
    const int*   labels  = (const int*)d_in[0];
    const float* logits  = (const float*)d_in[1];
    const float* weights = (const float*)d_in[2];
    float* out     = (float*)d_out;
    float* partial = (float*)d_ws;

    const int n  = in_sizes[0];
    const int n8 = n / 8;

    int nb = (int)(ws_size / (2 * BINS * sizeof(float)));
    if (nb > K1_MAXBLOCKS) nb = K1_MAXBLOCKS;
    if (nb < 1) nb = 1;

    ghm_partial<<<nb, K1_THREADS, 0, stream>>>(labels, logits, weights, partial, n8, n, nb);
    ghm_final<<<1, 1024, 0, stream>>>(partial, out, nb);
}

// Round 5
// 92.358 us; speedup vs baseline: 3.1709x; 3.1709x over previous
//
#include <hip/hip_runtime.h>
#include <math.h>

#define BINS 10
#define K1_THREADS 256
#define K1_MAXBLOCKS 1024

// Per-element: xs = label ? -x : x ; p_norm = sigmoid(xs) ; bce = softplus(xs)
//            = max(xs,0) + log(1+exp(-|xs|)).
// Counts go to SALU: ballot+popcount into wave-uniform accumulators.
// Sums stay VALU: one cmp+cndmask+add per bin (compare shared with ballot).
__device__ __forceinline__ void ghm_elem(int y, float x, float w,
                                         float* __restrict__ sm,
                                         unsigned* __restrict__ cnt) {
    float xs = (y == 1) ? -x : x;
    float e  = __expf(-fabsf(xs));            // exp(-|xs|) in (0,1]
    float d  = 1.0f + e;                      // in [1,2] -> log always safe
    float r  = __builtin_amdgcn_rcpf(d);      // v_rcp_f32
    float pn = (xs >= 0.0f) ? r : e * r;      // sigmoid(xs) == p_norm
    int bin  = (int)(pn * 10.0f);             // pn>0 -> trunc == floor
    bin = bin > (BINS - 1) ? (BINS - 1) : bin;
    bin = (w > 0.0f) ? bin : 15;              // invalid -> matches no bin
    float bce = fmaxf(xs, 0.0f) + __logf(d);  // softplus(xs)
    #pragma unroll
    for (int b = 0; b < BINS; ++b) {
        bool hit = (bin == b);
        cnt[b] += (unsigned)__popcll(__ballot(hit));  // SALU: s_bcnt1 + s_add
        sm[b]  += hit ? bce : 0.0f;                   // VALU: cndmask + add
    }
}

// Kernel 1: per-block partial {count, sum(bce*valid)} per bin.
// partial layout in d_ws: rows 0..9 = counts, rows 10..19 = sums, nb cols.
__global__ __launch_bounds__(K1_THREADS, 4) void ghm_partial(
    const int*   __restrict__ labels,
    const float* __restrict__ logits,
    const float* __restrict__ weights,
    float*       __restrict__ partial,
    int n8, int n, int nb)
{
    const int tid = threadIdx.x;

    float    sm[BINS];
    unsigned cnt[BINS];   // wave-uniform (ballot): lane 0's copy is authoritative
    #pragma unroll
    for (int b = 0; b < BINS; ++b) { sm[b] = 0.0f; cnt[b] = 0u; }

    const int4*   lab4 = (const int4*)labels;
    const float4* log4 = (const float4*)logits;
    const float4* w4   = (const float4*)weights;

    const int stride = gridDim.x * blockDim.x;
    for (int i = blockIdx.x * blockDim.x + tid; i < n8; i += stride) {
        const int b0 = i * 2;
        // 6 independent dwordx4 loads in flight (96 B/lane)
        int4   lb0 = lab4[b0],  lb1 = lab4[b0 + 1];
        float4 xv0 = log4[b0],  xv1 = log4[b0 + 1];
        float4 wv0 = w4[b0],    wv1 = w4[b0 + 1];

        ghm_elem(lb0.x, xv0.x, wv0.x, sm, cnt);
        ghm_elem(lb0.y, xv0.y, wv0.y, sm, cnt);
        ghm_elem(lb0.z, xv0.z, wv0.z, sm, cnt);
        ghm_elem(lb0.w, xv0.w, wv0.w, sm, cnt);
        ghm_elem(lb1.x, xv1.x, wv1.x, sm, cnt);
        ghm_elem(lb1.y, xv1.y, wv1.y, sm, cnt);
        ghm_elem(lb1.z, xv1.z, wv1.z, sm, cnt);
        ghm_elem(lb1.w, xv1.w, wv1.w, sm, cnt);
    }

    // scalar tail (n % 8), block 0 only (n divisible by 8 for this shape)
    const int rem_start = n8 * 8;
    if (blockIdx.x == 0 && tid < (n - rem_start)) {
        const int idx = rem_start + tid;
        ghm_elem(labels[idx], logits[idx], weights[idx], sm, cnt);
    }

    // wave reduce: sums via shuffle; counts are already wave totals (lane 0 valid:
    // in a grid-stride loop lane 0 has the lowest index, so it is active for
    // every ballot any wave-mate executes)
    #pragma unroll
    for (int off = 32; off > 0; off >>= 1) {
        #pragma unroll
        for (int b = 0; b < BINS; ++b)
            sm[b] += __shfl_down(sm[b], off);
    }

    __shared__ float redc[K1_THREADS / 64][BINS];
    __shared__ float reds[K1_THREADS / 64][BINS];
    const int wave = tid >> 6, lane = tid & 63;
    if (lane == 0) {
        #pragma unroll
        for (int b = 0; b < BINS; ++b) {
            redc[wave][b] = (float)cnt[b];
            reds[wave][b] = sm[b];
        }
    }
    __syncthreads();

    if (tid < BINS) {
        float c = 0.0f, s = 0.0f;
        #pragma unroll
        for (int wv = 0; wv < K1_THREADS / 64; ++wv) {
            c += redc[wv][tid];
            s += reds[wv][tid];
        }
        partial[tid * nb + blockIdx.x]          = c;
        partial[(BINS + tid) * nb + blockIdx.x] = s;
    }
}

// Kernel 2: reduce nb partial columns, finalize scalar.
__global__ __launch_bounds__(1024) void ghm_final(
    const float* __restrict__ partial, float* __restrict__ out, int nb)
{
    const int tid = threadIdx.x;
    float acc[2 * BINS];
    #pragma unroll
    for (int b = 0; b < 2 * BINS; ++b) acc[b] = 0.0f;
    for (int j = tid; j < nb; j += 1024) {
        #pragma unroll
        for (int b = 0; b < 2 * BINS; ++b)
            acc[b] += partial[b * nb + j];     // coalesced row loads
    }

    #pragma unroll
    for (int off = 32; off > 0; off >>= 1) {
        #pragma unroll
        for (int b = 0; b < 2 * BINS; ++b)
            acc[b] += __shfl_down(acc[b], off);
    }

    __shared__ float red[16][2 * BINS];
    const int wave = tid >> 6, lane = tid & 63;
    if (lane == 0) {
        #pragma unroll
        for (int b = 0; b < 2 * BINS; ++b) red[wave][b] = acc[b];
    }
    __syncthreads();

    if (tid == 0) {
        float cnt[BINS], s[BINS];
        #pragma unroll
        for (int b = 0; b < BINS; ++b) { cnt[b] = 0.0f; s[b] = 0.0f; }
        for (int wv = 0; wv < 16; ++wv) {
            #pragma unroll
            for (int b = 0; b < BINS; ++b) {
                cnt[b] += red[wv][b];
                s[b]   += red[wv][BINS + b];
            }
        }
        float nn = 0.0f, res = 0.0f;
        #pragma unroll
        for (int b = 0; b < BINS; ++b) {
            if (cnt[b] > 0.0f) {
                nn  += 1.0f;
                res += s[b] / fmaxf(cnt[b], 1.0f);
            }
        }
        if (nn > 0.0f) res /= nn;   // total_num cancels exactly in the algebra
        out[0] = res;
    }
}

extern "C" void kernel_launch(void* const* d_in, const int* in_sizes, int n_in,
                              void* d_out, int out_size, void* d_ws, size_t ws_size,
                              hipStream_t stream) {
    const int*   labels  = (const int*)d_in[0];
    const float* logits  = (const float*)d_in[1];
    const float* weights = (const float*)d_in[2];
    float* out     = (float*)d_out;
    float* partial = (float*)d_ws;

    const int n  = in_sizes[0];
    const int n8 = n / 8;

    int nb = (int)(ws_size / (2 * BINS * sizeof(float)));
    if (nb > K1_MAXBLOCKS) nb = K1_MAXBLOCKS;
    if (nb < 1) nb = 1;

    ghm_partial<<<nb, K1_THREADS, 0, stream>>>(labels, logits, weights, partial, n8, n, nb);
    ghm_final<<<1, 1024, 0, stream>>>(partial, out, nb);
}

// Round 6
// 89.480 us; speedup vs baseline: 3.2729x; 1.0322x over previous
//
#include <hip/hip_runtime.h>
#include <math.h>

#define BINS 10
#define K1_THREADS 256
#define K1_MAXBLOCKS 2048

// Cumulative-threshold formulation:
//   bin(x) >= b  <=>  sigmoid(xs) >= b/10  <=>  xs >= TH[b] = ln(b/(10-b))
// Accumulators (per thread):
//   C[0] = # valid;           C[b] = # valid with xs >= TH[b]   (b=1..9)
//   G[0] = sum bce (valid);   G[b] = sum bce*[xs >= TH[b]]      (b=1..9)
// Invalid elements are poisoned xs = -1e30: bce evaluates to EXACTLY 0
// (fmax(-1e30,0)=0, exp->0, log(1)=0) and all thresholds fail -> they
// contribute nothing anywhere. No extra masking ops.
// Per-bin reconstruction happens in kernel 2.
__device__ const float TH[10] = {
    0.0f,            // unused
    -2.19722458f,    // ln(1/9)
    -1.38629436f,    // ln(2/8)
    -0.84729786f,    // ln(3/7)
    -0.40546511f,    // ln(4/6)
     0.0f,           // ln(5/5)
     0.40546511f,
     0.84729786f,
     1.38629436f,
     2.19722458f
};

__device__ __forceinline__ void ghm_elem(int y, float x, float w,
                                         float* __restrict__ G,
                                         unsigned* __restrict__ C) {
    // sign flip via integer xor (no vcc): labels are 0/1
    float xs = __int_as_float(__float_as_int(x) ^ (y << 31));
    bool  v  = (w > 0.0f);
    xs = v ? xs : -1e30f;                 // poison: bce==0, fails all thresholds
    C[0] += v;
    float e   = __expf(-fabsf(xs));       // exp(-|xs|) in [0,1]
    float d   = 1.0f + e;
    float bce = fmaxf(xs, 0.0f) + __logf(d);   // softplus(xs); ==0 when poisoned
    G[0] += bce;
    #pragma unroll
    for (int b = 1; b < BINS; ++b) {
        bool ge = (xs >= TH[b]);          // one compare shared by count & sum
        C[b] += ge;
        G[b] += ge ? bce : 0.0f;
    }
}

// Kernel 1: software-pipelined streaming pass; per-block partials.
// partial layout in d_ws: rows 0..9 = cumulative counts (C), rows 10..19 = G,
// nb columns.
__global__ __launch_bounds__(K1_THREADS, 8) void ghm_partial(
    const int*   __restrict__ labels,
    const float* __restrict__ logits,
    const float* __restrict__ weights,
    float*       __restrict__ partial,
    int nbatch, int n, int nb)
{
    const int tid  = blockIdx.x * K1_THREADS + threadIdx.x;
    const int T    = gridDim.x * K1_THREADS;   // total threads

    float    G[BINS];
    unsigned C[BINS];
    #pragma unroll
    for (int b = 0; b < BINS; ++b) { G[b] = 0.0f; C[b] = 0u; }

    const int4*   lab4 = (const int4*)labels;
    const float4* log4 = (const float4*)logits;
    const float4* w4   = (const float4*)weights;

    // ---- 2-deep software pipeline over batches of 4 elements ----
    int i = tid;                                // float4 index; same for all 3 streams
    if (nbatch > 0) {
        int4   a0 = lab4[i];
        float4 x0 = log4[i];
        float4 v0 = w4[i];
        #pragma unroll 2
        for (int bt = 1; bt < nbatch; ++bt) {
            const int i1 = i + T;
            int4   a1 = lab4[i1];               // issue next batch's loads
            float4 x1 = log4[i1];
            float4 v1 = w4[i1];
            ghm_elem(a0.x, x0.x, v0.x, G, C);   // process current batch
            ghm_elem(a0.y, x0.y, v0.y, G, C);
            ghm_elem(a0.z, x0.z, v0.z, G, C);
            ghm_elem(a0.w, x0.w, v0.w, G, C);
            a0 = a1; x0 = x1; v0 = v1; i = i1;
        }
        ghm_elem(a0.x, x0.x, v0.x, G, C);
        ghm_elem(a0.y, x0.y, v0.y, G, C);
        ghm_elem(a0.z, x0.z, v0.z, G, C);
        ghm_elem(a0.w, x0.w, v0.w, G, C);
    }

    // ---- scalar tail: elements beyond nbatch*T*4 (uniform per thread) ----
    for (int e = nbatch * T * 4 + tid; e < n; e += T)
        ghm_elem(labels[e], logits[e], weights[e], G, C);

    // ---- block reduction (runs once; cost negligible) ----
    float g[BINS], c[BINS];
    #pragma unroll
    for (int b = 0; b < BINS; ++b) { g[b] = G[b]; c[b] = (float)C[b]; }
    #pragma unroll
    for (int off = 32; off > 0; off >>= 1) {
        #pragma unroll
        for (int b = 0; b < BINS; ++b) {
            c[b] += __shfl_down(c[b], off);
            g[b] += __shfl_down(g[b], off);
        }
    }
    __shared__ float redc[K1_THREADS / 64][BINS];
    __shared__ float redg[K1_THREADS / 64][BINS];
    const int wave = threadIdx.x >> 6, lane = threadIdx.x & 63;
    if (lane == 0) {
        #pragma unroll
        for (int b = 0; b < BINS; ++b) { redc[wave][b] = c[b]; redg[wave][b] = g[b]; }
    }
    __syncthreads();
    if (threadIdx.x < BINS) {
        float cc = 0.0f, gg = 0.0f;
        #pragma unroll
        for (int wv = 0; wv < K1_THREADS / 64; ++wv) {
            cc += redc[wv][threadIdx.x];
            gg += redg[wv][threadIdx.x];
        }
        partial[threadIdx.x * nb + blockIdx.x]          = cc;
        partial[(BINS + threadIdx.x) * nb + blockIdx.x] = gg;
    }
}

// Kernel 2: reduce nb columns, reconstruct per-bin {C_b, S_b}, finalize.
__global__ __launch_bounds__(1024) void ghm_final(
    const float* __restrict__ partial, float* __restrict__ out, int nb)
{
    const int tid = threadIdx.x;
    float acc[2 * BINS];
    #pragma unroll
    for (int b = 0; b < 2 * BINS; ++b) acc[b] = 0.0f;
    for (int j = tid; j < nb; j += 1024) {
        #pragma unroll
        for (int b = 0; b < 2 * BINS; ++b)
            acc[b] += partial[b * nb + j];     // coalesced row loads
    }

    #pragma unroll
    for (int off = 32; off > 0; off >>= 1) {
        #pragma unroll
        for (int b = 0; b < 2 * BINS; ++b)
            acc[b] += __shfl_down(acc[b], off);
    }

    __shared__ float red[16][2 * BINS];
    const int wave = tid >> 6, lane = tid & 63;
    if (lane == 0) {
        #pragma unroll
        for (int b = 0; b < 2 * BINS; ++b) red[wave][b] = acc[b];
    }
    __syncthreads();

    if (tid == 0) {
        float cum_c[BINS], cum_g[BINS];
        #pragma unroll
        for (int b = 0; b < BINS; ++b) { cum_c[b] = 0.0f; cum_g[b] = 0.0f; }
        for (int wv = 0; wv < 16; ++wv) {
            #pragma unroll
            for (int b = 0; b < BINS; ++b) {
                cum_c[b] += red[wv][b];
                cum_g[b] += red[wv][BINS + b];
            }
        }
        // de-cumulate: bin b in [0..8]: C_b = cum[b]-cum[b+1]; bin 9 = cum[9]
        // (cum_c[0] = n_valid, cum_g[0] = total valid bce sum)
        float nn = 0.0f, res = 0.0f;
        #pragma unroll
        for (int b = 0; b < BINS; ++b) {
            float Cb = (b < BINS - 1) ? (cum_c[b] - cum_c[b + 1]) : cum_c[b];
            float Sb = (b < BINS - 1) ? (cum_g[b] - cum_g[b + 1]) : cum_g[b];
            if (Cb > 0.5f) {
                nn  += 1.0f;
                res += Sb / Cb;
            }
        }
        if (nn > 0.0f) res /= nn;   // total_num cancels exactly in the algebra
        out[0] = res;
    }
}

extern "C" void kernel_launch(void* const* d_in, const int* in_sizes, int n_in,
                              void* d_out, int out_size, void* d_ws, size_t ws_size,
                              hipStream_t stream) {
    const int*   labels  = (const int*)d_in[0];
    const float* logits  = (const float*)d_in[1];
    const float* weights = (const float*)d_in[2];
    float* out     = (float*)d_out;
    float* partial = (float*)d_ws;

    const int n = in_sizes[0];

    int nb = (int)(ws_size / (2 * BINS * sizeof(float)));
    if (nb > K1_MAXBLOCKS) nb = K1_MAXBLOCKS;
    if (nb < 1) nb = 1;

    const int T      = nb * K1_THREADS;
    const int nbatch = n / (4 * T);            // full 4-elem batches per thread

    ghm_partial<<<nb, K1_THREADS, 0, stream>>>(labels, logits, weights, partial,
                                               nbatch, n, nb);
    ghm_final<<<1, 1024, 0, stream>>>(partial, out, nb);
}

// Round 7
// 83.840 us; speedup vs baseline: 3.4931x; 1.0673x over previous
//
#include <hip/hip_runtime.h>
#include <math.h>

#define BINS 10
#define K1_THREADS 256
#define WPB   4        // waves per block
#define DEPTH 3        // tiles prefetched ahead
#define NSLOT 4        // LDS ring slots per wave (= DEPTH+1)
#define TILE  256      // elements per wave-tile (64 lanes x 4)
#define SLOT_BYTES 3072  // 3 streams x 1 KiB

// Cumulative-threshold formulation (same as R6):
//   bin(x) >= b <=> xs >= TH[b] = ln(b/(10-b));  invalid poisoned to xs=-1e30
//   (bce evaluates to exactly 0, fails all thresholds).
// Rows 0..9 of partial = cumulative counts, rows 10..19 = cumulative bce sums.
__device__ __forceinline__ void ghm_elem(int y, float x, float w,
                                         float* __restrict__ G,
                                         float* __restrict__ C) {
    constexpr float TH[10] = {
        0.0f, -2.19722458f, -1.38629436f, -0.84729786f, -0.40546511f,
        0.0f,  0.40546511f,  0.84729786f,  1.38629436f,  2.19722458f };
    float xs = __int_as_float(__float_as_int(x) ^ (y << 31));
    bool  v  = (w > 0.0f);
    xs = v ? xs : -1e30f;
    C[0] += v ? 1.0f : 0.0f;
    float e   = __expf(-fabsf(xs));             // exp(-|xs|) in [0,1]
    float bce = fmaxf(xs, 0.0f) + __logf(1.0f + e);  // softplus; 0 when poisoned
    G[0] += bce;
    #pragma unroll
    for (int b = 1; b < BINS; ++b) {
        bool ge = (xs >= TH[b]);
        C[b] += ge ? 1.0f : 0.0f;
        G[b] += ge ? bce : 0.0f;
    }
}

#define GLD_LDS16(gsrc, ldst)                                                  \
    __builtin_amdgcn_global_load_lds(                                          \
        (const __attribute__((address_space(1))) void*)(gsrc),                 \
        (__attribute__((address_space(3))) void*)(ldst), 16, 0, 0)

__global__ __launch_bounds__(K1_THREADS) void ghm_partial(
    const int*   __restrict__ labels,
    const float* __restrict__ logits,
    const float* __restrict__ weights,
    float*       __restrict__ partial,
    int NT, int n, int nb, int covered)
{
    __shared__ __align__(16) char ldsbuf[WPB][NSLOT][SLOT_BYTES];
    __shared__ float redc[WPB][BINS], redg[WPB][BINS];

    const int tid  = threadIdx.x;
    const int wid  = tid >> 6;
    const int lane = tid & 63;
    const int wgl  = blockIdx.x * WPB + wid;     // global wave id
    const int base0 = wgl * NT * TILE;           // this wave's first element

    float G[BINS], C[BINS];
    #pragma unroll
    for (int b = 0; b < BINS; ++b) { G[b] = 0.0f; C[b] = 0.0f; }

    const int*   labp = labels  + base0;
    const float* logp = logits  + base0;
    const float* wtp  = weights + base0;

    // stage tile k: 3 x global_load_lds_dwordx4 (wave-uniform LDS base,
    // per-lane global addr); lane i's 16 B land at slot + i*16.
    auto stage = [&](int k) {
        char* slot = &ldsbuf[wid][k & (NSLOT - 1)][0];
        const int off = k * TILE + lane * 4;
        GLD_LDS16(labp + off, slot);
        GLD_LDS16(logp + off, slot + 1024);
        GLD_LDS16(wtp  + off, slot + 2048);
    };
    // consume tile k: lane reads back exactly the bytes it staged.
    auto consume = [&](int k) {
        const char* slot = &ldsbuf[wid][k & (NSLOT - 1)][0];
        int4   lb = *(const int4*)  (slot +        lane * 16);
        float4 xv = *(const float4*)(slot + 1024 + lane * 16);
        float4 wv = *(const float4*)(slot + 2048 + lane * 16);
        ghm_elem(lb.x, xv.x, wv.x, G, C);
        ghm_elem(lb.y, xv.y, wv.y, G, C);
        ghm_elem(lb.z, xv.z, wv.z, G, C);
        ghm_elem(lb.w, xv.w, wv.w, G, C);
    };

    if (NT > DEPTH) {
        stage(0); stage(1); stage(2);            // 9 loads in flight
        for (int t = 0; t < NT - DEPTH; ++t) {
            stage(t + DEPTH);                    // <=12 outstanding
            // newest 9 = tiles t+1..t+3 -> tile t's 3 loads are drained
            asm volatile("s_waitcnt vmcnt(9)" ::: "memory");
            consume(t);
        }
        asm volatile("s_waitcnt vmcnt(6)" ::: "memory");
        consume(NT - 3);
        asm volatile("s_waitcnt vmcnt(3)" ::: "memory");
        consume(NT - 2);
        asm volatile("s_waitcnt vmcnt(0)" ::: "memory");
        consume(NT - 1);
    } else {
        for (int t = 0; t < NT; ++t) {
            stage(t);
            asm volatile("s_waitcnt vmcnt(0)" ::: "memory");
            consume(t);
        }
    }

    // generic tail: elements not covered by the tiled region (0 for this shape)
    const int T = nb * K1_THREADS;
    for (int e2 = covered + blockIdx.x * K1_THREADS + tid; e2 < n; e2 += T)
        ghm_elem(labels[e2], logits[e2], weights[e2], G, C);

    // wave shuffle reduce, then cross-wave via LDS
    #pragma unroll
    for (int off = 32; off > 0; off >>= 1) {
        #pragma unroll
        for (int b = 0; b < BINS; ++b) {
            C[b] += __shfl_down(C[b], off);
            G[b] += __shfl_down(G[b], off);
        }
    }
    if (lane == 0) {
        #pragma unroll
        for (int b = 0; b < BINS; ++b) { redc[wid][b] = C[b]; redg[wid][b] = G[b]; }
    }
    __syncthreads();
    if (tid < BINS) {
        float cc = 0.0f, gg = 0.0f;
        #pragma unroll
        for (int wv = 0; wv < WPB; ++wv) { cc += redc[wv][tid]; gg += redg[wv][tid]; }
        partial[tid * nb + blockIdx.x]          = cc;
        partial[(BINS + tid) * nb + blockIdx.x] = gg;
    }
}

// Kernel 2: reduce nb columns, de-cumulate, finalize scalar.
__global__ __launch_bounds__(1024) void ghm_final(
    const float* __restrict__ partial, float* __restrict__ out, int nb)
{
    const int tid = threadIdx.x;
    float acc[2 * BINS];
    #pragma unroll
    for (int b = 0; b < 2 * BINS; ++b) acc[b] = 0.0f;
    for (int j = tid; j < nb; j += 1024) {
        #pragma unroll
        for (int b = 0; b < 2 * BINS; ++b)
            acc[b] += partial[b * nb + j];
    }
    #pragma unroll
    for (int off = 32; off > 0; off >>= 1) {
        #pragma unroll
        for (int b = 0; b < 2 * BINS; ++b)
            acc[b] += __shfl_down(acc[b], off);
    }
    __shared__ float red[16][2 * BINS];
    const int wave = tid >> 6, lane = tid & 63;
    if (lane == 0) {
        #pragma unroll
        for (int b = 0; b < 2 * BINS; ++b) red[wave][b] = acc[b];
    }
    __syncthreads();
    if (tid == 0) {
        float cum_c[BINS], cum_g[BINS];
        #pragma unroll
        for (int b = 0; b < BINS; ++b) { cum_c[b] = 0.0f; cum_g[b] = 0.0f; }
        for (int wv = 0; wv < 16; ++wv) {
            #pragma unroll
            for (int b = 0; b < BINS; ++b) {
                cum_c[b] += red[wv][b];
                cum_g[b] += red[wv][BINS + b];
            }
        }
        float nn = 0.0f, res = 0.0f;
        #pragma unroll
        for (int b = 0; b < BINS; ++b) {
            float Cb = (b < BINS - 1) ? (cum_c[b] - cum_c[b + 1]) : cum_c[b];
            float Sb = (b < BINS - 1) ? (cum_g[b] - cum_g[b + 1]) : cum_g[b];
            if (Cb > 0.5f) { nn += 1.0f; res += Sb / Cb; }
        }
        if (nn > 0.0f) res /= nn;   // total_num cancels exactly
        out[0] = res;
    }
}

extern "C" void kernel_launch(void* const* d_in, const int* in_sizes, int n_in,
                              void* d_out, int out_size, void* d_ws, size_t ws_size,
                              hipStream_t stream) {
    const int*   labels  = (const int*)d_in[0];
    const float* logits  = (const float*)d_in[1];
    const float* weights = (const float*)d_in[2];
    float* out     = (float*)d_out;
    float* partial = (float*)d_ws;

    const int n = in_sizes[0];

    int nb = 1440;                                    // 5760 waves -> NT=16 for this shape
    const size_t row_bytes = 2 * BINS * sizeof(float);
    if (ws_size < row_bytes * 1440) nb = 720;
    if (ws_size < row_bytes * 720)  nb = 360;

    const int NT      = n / (nb * WPB * TILE);        // tiles per wave
    const int covered = NT * nb * WPB * TILE;

    ghm_partial<<<nb, K1_THREADS, 0, stream>>>(labels, logits, weights, partial,
                                               NT, n, nb, covered);
    ghm_final<<<1, 1024, 0, stream>>>(partial, out, nb);
}

// Round 8
// 74.216 us; speedup vs baseline: 3.9460x; 1.1297x over previous
//
#include <hip/hip_runtime.h>
#include <math.h>

#define BINS 10
#define K1_THREADS 256

typedef float f32x4 __attribute__((ext_vector_type(4)));
typedef int   i32x4 __attribute__((ext_vector_type(4)));

// Cumulative-threshold formulation (verified absmax 0.0 in R6/R7):
//   bin(x) >= b <=> xs >= TH[b] = ln(b/(10-b)); invalid poisoned xs=-1e30
//   (bce becomes exactly 0 and fails all thresholds -> contributes nothing).
// partial rows 0..9 = cumulative counts, rows 10..19 = cumulative bce sums.
__device__ __forceinline__ void ghm_elem(int y, float x, float w,
                                         float* __restrict__ G,
                                         float* __restrict__ C) {
    constexpr float TH[10] = {
        0.0f, -2.19722458f, -1.38629436f, -0.84729786f, -0.40546511f,
        0.0f,  0.40546511f,  0.84729786f,  1.38629436f,  2.19722458f };
    float xs = __int_as_float(__float_as_int(x) ^ (y << 31));
    bool  v  = (w > 0.0f);
    xs = v ? xs : -1e30f;
    C[0] += v ? 1.0f : 0.0f;
    float e   = __expf(-fabsf(xs));                  // exp(-|xs|) in [0,1]
    float bce = fmaxf(xs, 0.0f) + __logf(1.0f + e);  // softplus; 0 when poisoned
    G[0] += bce;
    #pragma unroll
    for (int b = 1; b < BINS; ++b) {
        bool ge = (xs >= TH[b]);
        C[b] += ge ? 1.0f : 0.0f;
        G[b] += ge ? bce : 0.0f;
    }
}

// Inline-asm loads: the compiler CANNOT sink these to their uses (the R6
// failure mode), so the depth-3 pipeline actually stays in flight.
#define GLOAD(dst, ptr) \
    asm volatile("global_load_dwordx4 %0, %1, off" : "=v"(dst) : "v"(ptr))

// Counted drain + scheduling fence (rule #18: hipcc hoists register-only ops
// past inline-asm waitcnt unless a sched_barrier follows).
#define VMWAIT(N)                                              \
    do { asm volatile("s_waitcnt vmcnt(" #N ")" ::: "memory"); \
         __builtin_amdgcn_sched_barrier(0); } while (0)

#define CONSUME(l, xv, wv)                        \
    do {                                          \
        ghm_elem(l[0], xv[0], wv[0], G, C);       \
        ghm_elem(l[1], xv[1], wv[1], G, C);       \
        ghm_elem(l[2], xv[2], wv[2], G, C);       \
        ghm_elem(l[3], xv[3], wv[3], G, C);       \
    } while (0)

__global__ __launch_bounds__(K1_THREADS, 6) void ghm_partial(
    const int*   __restrict__ labels,
    const float* __restrict__ logits,
    const float* __restrict__ weights,
    float*       __restrict__ partial,
    int n4, int n, int nb)
{
    const int tid = blockIdx.x * K1_THREADS + threadIdx.x;
    const int T   = gridDim.x * K1_THREADS;

    float G[BINS], C[BINS];
    #pragma unroll
    for (int b = 0; b < BINS; ++b) { G[b] = 0.0f; C[b] = 0.0f; }

    const i32x4* lab4 = (const i32x4*)labels;
    const f32x4* log4 = (const f32x4*)logits;
    const f32x4* w4   = (const f32x4*)weights;

    const int nfull = n4 / T;      // uniform full batches per thread
    int consumed = 0;

    if (nfull >= 3) {
        i32x4 lA, lB, lC;
        f32x4 xA, xB, xC, wA, wB, wC;
        long ia = tid;
        // prologue: 3 batches x 3 streams = 9 loads in flight
        GLOAD(lA, lab4 + ia);         GLOAD(xA, log4 + ia);         GLOAD(wA, w4 + ia);
        GLOAD(lB, lab4 + ia + T);     GLOAD(xB, log4 + ia + T);     GLOAD(wB, w4 + ia + T);
        GLOAD(lC, lab4 + ia + 2*T);   GLOAD(xC, log4 + ia + 2*T);   GLOAD(wC, w4 + ia + 2*T);

        const int s = (nfull - 3) / 3;    // steady iterations (3 batches each)
        long inx = ia + 3L * T;           // next issue index
        for (int it = 0; it < s; ++it) {
            VMWAIT(6);                    // oldest 3 (A) drained
            CONSUME(lA, xA, wA);
            GLOAD(lA, lab4 + inx); GLOAD(xA, log4 + inx); GLOAD(wA, w4 + inx);
            inx += T;
            VMWAIT(6);                    // B drained
            CONSUME(lB, xB, wB);
            GLOAD(lB, lab4 + inx); GLOAD(xB, log4 + inx); GLOAD(wB, w4 + inx);
            inx += T;
            VMWAIT(6);                    // C drained
            CONSUME(lC, xC, wC);
            GLOAD(lC, lab4 + inx); GLOAD(xC, log4 + inx); GLOAD(wC, w4 + inx);
            inx += T;
        }
        VMWAIT(6); CONSUME(lA, xA, wA);
        VMWAIT(3); CONSUME(lB, xB, wB);
        VMWAIT(0); CONSUME(lC, xC, wC);   // all drained -> clean vmcnt state
        consumed = 3 + 3 * s;
    }

    // leftover batches (nfull % 3, plus any ragged region) — plain loads
    for (long i2 = (long)tid + (long)consumed * T; i2 < n4; i2 += T) {
        i32x4 lb = lab4[i2];
        f32x4 xv = log4[i2];
        f32x4 wv = w4[i2];
        CONSUME(lb, xv, wv);
    }
    // scalar tail (n % 4 == 0 for this shape; kept generic)
    for (int e2 = n4 * 4 + tid; e2 < n; e2 += T)
        ghm_elem(labels[e2], logits[e2], weights[e2], G, C);

    // wave shuffle reduce, then cross-wave via (tiny) LDS
    #pragma unroll
    for (int off = 32; off > 0; off >>= 1) {
        #pragma unroll
        for (int b = 0; b < BINS; ++b) {
            C[b] += __shfl_down(C[b], off);
            G[b] += __shfl_down(G[b], off);
        }
    }
    __shared__ float redc[K1_THREADS / 64][BINS];
    __shared__ float redg[K1_THREADS / 64][BINS];
    const int wid = threadIdx.x >> 6, lane = threadIdx.x & 63;
    if (lane == 0) {
        #pragma unroll
        for (int b = 0; b < BINS; ++b) { redc[wid][b] = C[b]; redg[wid][b] = G[b]; }
    }
    __syncthreads();
    if (threadIdx.x < BINS) {
        float cc = 0.0f, gg = 0.0f;
        #pragma unroll
        for (int wv = 0; wv < K1_THREADS / 64; ++wv) {
            cc += redc[wv][threadIdx.x];
            gg += redg[wv][threadIdx.x];
        }
        partial[threadIdx.x * nb + blockIdx.x]          = cc;
        partial[(BINS + threadIdx.x) * nb + blockIdx.x] = gg;
    }
}

// Kernel 2: reduce nb columns, de-cumulate, finalize scalar.
__global__ __launch_bounds__(1024) void ghm_final(
    const float* __restrict__ partial, float* __restrict__ out, int nb)
{
    const int tid = threadIdx.x;
    float acc[2 * BINS];
    #pragma unroll
    for (int b = 0; b < 2 * BINS; ++b) acc[b] = 0.0f;
    for (int j = tid; j < nb; j += 1024) {
        #pragma unroll
        for (int b = 0; b < 2 * BINS; ++b)
            acc[b] += partial[b * nb + j];
    }
    #pragma unroll
    for (int off = 32; off > 0; off >>= 1) {
        #pragma unroll
        for (int b = 0; b < 2 * BINS; ++b)
            acc[b] += __shfl_down(acc[b], off);
    }
    __shared__ float red[16][2 * BINS];
    const int wave = tid >> 6, lane = tid & 63;
    if (lane == 0) {
        #pragma unroll
        for (int b = 0; b < 2 * BINS; ++b) red[wave][b] = acc[b];
    }
    __syncthreads();
    if (tid == 0) {
        float cum_c[BINS], cum_g[BINS];
        #pragma unroll
        for (int b = 0; b < BINS; ++b) { cum_c[b] = 0.0f; cum_g[b] = 0.0f; }
        for (int wv = 0; wv < 16; ++wv) {
            #pragma unroll
            for (int b = 0; b < BINS; ++b) {
                cum_c[b] += red[wv][b];
                cum_g[b] += red[wv][BINS + b];
            }
        }
        float nn = 0.0f, res = 0.0f;
        #pragma unroll
        for (int b = 0; b < BINS; ++b) {
            float Cb = (b < BINS - 1) ? (cum_c[b] - cum_c[b + 1]) : cum_c[b];
            float Sb = (b < BINS - 1) ? (cum_g[b] - cum_g[b + 1]) : cum_g[b];
            if (Cb > 0.5f) { nn += 1.0f; res += Sb / Cb; }
        }
        if (nn > 0.0f) res /= nn;   // total_num cancels exactly
        out[0] = res;
    }
}

extern "C" void kernel_launch(void* const* d_in, const int* in_sizes, int n_in,
                              void* d_out, int out_size, void* d_ws, size_t ws_size,
                              hipStream_t stream) {
    const int*   labels  = (const int*)d_in[0];
    const float* logits  = (const float*)d_in[1];
    const float* weights = (const float*)d_in[2];
    float* out     = (float*)d_out;
    float* partial = (float*)d_ws;

    const int n  = in_sizes[0];
    const int n4 = n / 4;

    int nb = 1440;                     // T=368,640 -> nfull=16 for this shape
    const size_t row_bytes = 2 * BINS * sizeof(float);
    if (ws_size < row_bytes * 1440) nb = 720;
    if (ws_size < row_bytes * 720)  nb = 360;

    ghm_partial<<<nb, K1_THREADS, 0, stream>>>(labels, logits, weights, partial,
                                               n4, n, nb);
    ghm_final<<<1, 1024, 0, stream>>>(partial, out, nb);
}

// Round 13
// 72.905 us; speedup vs baseline: 4.0170x; 1.0180x over previous
//
#include <hip/hip_runtime.h>
#include <math.h>

#define BINS 10
#define K1_THREADS 256

typedef float f32x4 __attribute__((ext_vector_type(4)));
typedef int   i32x4 __attribute__((ext_vector_type(4)));

// Cumulative-threshold formulation in LOG2 space:
//   t = xs * log2(e);  bin >= b  <=>  t >= TH2[b] = log2(b/(10-b))
//   softplus(xs) = ln2 * [ max(t,0) + log2(1 + 2^(-|t|)) ]  = ln2 * bce2
// We accumulate bce2 (scaled) and multiply the final scalar by ln2 in k2.
// Invalid elements poisoned t=-1e30: bce2 == 0 exactly, fails all thresholds.
// exp2f/log2f are the NATIVE v_exp_f32/v_log_f32 ops (no range-scaling mul).
// NOTE: __exp2f does not exist in HIP device code (R12 compile error) — use
// the plain libm names, OCML maps them 1:1 to the hardware instructions.
__device__ __forceinline__ void ghm_elem(int y, float x, float w,
                                         float* __restrict__ G,
                                         float* __restrict__ C) {
    constexpr float TH2[10] = {
        0.0f,
        -3.16992500f,    // log2(1/9)
        -2.0f,           // log2(2/8)
        -1.22239242f,    // log2(3/7)
        -0.58496250f,    // log2(4/6)
         0.0f,           // log2(5/5)
         0.58496250f,
         1.22239242f,
         2.0f,
         3.16992500f };
    float t = x * 1.44269504f;                   // x * log2(e)
    t = __int_as_float(__float_as_int(t) ^ (y << 31));  // label==1 -> -t
    bool v = (w > 0.0f);
    t = v ? t : -1e30f;
    C[0] += v ? 1.0f : 0.0f;
    float e2   = exp2f(-fabsf(t));               // v_exp_f32, src mods fold
    float bce2 = fmaxf(t, 0.0f) + log2f(1.0f + e2);   // v_log_f32
    G[0] += bce2;
    #pragma unroll
    for (int b = 1; b < BINS; ++b) {
        bool ge = (t >= TH2[b]);
        C[b] += ge ? 1.0f : 0.0f;
        G[b] += ge ? bce2 : 0.0f;
    }
}

// Inline-asm loads: the compiler CANNOT sink these to their uses, so the
// depth-3 pipeline actually stays in flight (R8-proven structure).
#define GLOAD(dst, ptr) \
    asm volatile("global_load_dwordx4 %0, %1, off" : "=v"(dst) : "v"(ptr))

// Counted drain + scheduling fence (rule #18).
#define VMWAIT(N)                                              \
    do { asm volatile("s_waitcnt vmcnt(" #N ")" ::: "memory"); \
         __builtin_amdgcn_sched_barrier(0); } while (0)

#define CONSUME(l, xv, wv)                        \
    do {                                          \
        ghm_elem(l[0], xv[0], wv[0], G, C);       \
        ghm_elem(l[1], xv[1], wv[1], G, C);       \
        ghm_elem(l[2], xv[2], wv[2], G, C);       \
        ghm_elem(l[3], xv[3], wv[3], G, C);       \
    } while (0)

__global__ __launch_bounds__(K1_THREADS, 6) void ghm_partial(
    const int*   __restrict__ labels,
    const float* __restrict__ logits,
    const float* __restrict__ weights,
    float*       __restrict__ partial,
    int n4, int n, int nb)
{
    const int tid = blockIdx.x * K1_THREADS + threadIdx.x;
    const int T   = gridDim.x * K1_THREADS;

    float G[BINS], C[BINS];
    #pragma unroll
    for (int b = 0; b < BINS; ++b) { G[b] = 0.0f; C[b] = 0.0f; }

    const i32x4* lab4 = (const i32x4*)labels;
    const f32x4* log4 = (const f32x4*)logits;
    const f32x4* w4   = (const f32x4*)weights;

    const int nfull = n4 / T;      // uniform full batches per thread
    int consumed = 0;

    if (nfull >= 3) {
        i32x4 lA, lB, lC;
        f32x4 xA, xB, xC, wA, wB, wC;
        long ia = tid;
        // prologue: 3 batches x 3 streams = 9 loads in flight
        GLOAD(lA, lab4 + ia);         GLOAD(xA, log4 + ia);         GLOAD(wA, w4 + ia);
        GLOAD(lB, lab4 + ia + T);     GLOAD(xB, log4 + ia + T);     GLOAD(wB, w4 + ia + T);
        GLOAD(lC, lab4 + ia + 2*T);   GLOAD(xC, log4 + ia + 2*T);   GLOAD(wC, w4 + ia + 2*T);

        const int s = (nfull - 3) / 3;    // steady iterations (3 batches each)
        long inx = ia + 3L * T;           // next issue index
        for (int it = 0; it < s; ++it) {
            VMWAIT(6);                    // oldest 3 (A) drained
            CONSUME(lA, xA, wA);
            GLOAD(lA, lab4 + inx); GLOAD(xA, log4 + inx); GLOAD(wA, w4 + inx);
            inx += T;
            VMWAIT(6);                    // B drained
            CONSUME(lB, xB, wB);
            GLOAD(lB, lab4 + inx); GLOAD(xB, log4 + inx); GLOAD(wB, w4 + inx);
            inx += T;
            VMWAIT(6);                    // C drained
            CONSUME(lC, xC, wC);
            GLOAD(lC, lab4 + inx); GLOAD(xC, log4 + inx); GLOAD(wC, w4 + inx);
            inx += T;
        }
        VMWAIT(6); CONSUME(lA, xA, wA);
        VMWAIT(3); CONSUME(lB, xB, wB);
        VMWAIT(0); CONSUME(lC, xC, wC);   // all drained -> clean vmcnt state
        consumed = 3 + 3 * s;
    }

    // leftover batches (nfull % 3, plus any ragged region) — plain loads
    for (long i2 = (long)tid + (long)consumed * T; i2 < n4; i2 += T) {
        i32x4 lb = lab4[i2];
        f32x4 xv = log4[i2];
        f32x4 wv = w4[i2];
        CONSUME(lb, xv, wv);
    }
    // scalar tail (n % 4 == 0 for this shape; kept generic)
    for (int e2i = n4 * 4 + tid; e2i < n; e2i += T)
        ghm_elem(labels[e2i], logits[e2i], weights[e2i], G, C);

    // wave shuffle reduce, then cross-wave via (tiny) LDS
    #pragma unroll
    for (int off = 32; off > 0; off >>= 1) {
        #pragma unroll
        for (int b = 0; b < BINS; ++b) {
            C[b] += __shfl_down(C[b], off);
            G[b] += __shfl_down(G[b], off);
        }
    }
    __shared__ float redc[K1_THREADS / 64][BINS];
    __shared__ float redg[K1_THREADS / 64][BINS];
    const int wid = threadIdx.x >> 6, lane = threadIdx.x & 63;
    if (lane == 0) {
        #pragma unroll
        for (int b = 0; b < BINS; ++b) { redc[wid][b] = C[b]; redg[wid][b] = G[b]; }
    }
    __syncthreads();
    if (threadIdx.x < BINS) {
        float cc = 0.0f, gg = 0.0f;
        #pragma unroll
        for (int wv = 0; wv < K1_THREADS / 64; ++wv) {
            cc += redc[wv][threadIdx.x];
            gg += redg[wv][threadIdx.x];
        }
        partial[threadIdx.x * nb + blockIdx.x]          = cc;
        partial[(BINS + threadIdx.x) * nb + blockIdx.x] = gg;
    }
}

// Kernel 2: reduce nb columns, de-cumulate, finalize scalar (x ln2 rescale).
__global__ __launch_bounds__(1024) void ghm_final(
    const float* __restrict__ partial, float* __restrict__ out, int nb)
{
    const int tid = threadIdx.x;
    float acc[2 * BINS];
    #pragma unroll
    for (int b = 0; b < 2 * BINS; ++b) acc[b] = 0.0f;
    for (int j = tid; j < nb; j += 1024) {
        #pragma unroll
        for (int b = 0; b < 2 * BINS; ++b)
            acc[b] += partial[b * nb + j];
    }
    #pragma unroll
    for (int off = 32; off > 0; off >>= 1) {
        #pragma unroll
        for (int b = 0; b < 2 * BINS; ++b)
            acc[b] += __shfl_down(acc[b], off);
    }
    __shared__ float red[16][2 * BINS];
    const int wave = tid >> 6, lane = tid & 63;
    if (lane == 0) {
        #pragma unroll
        for (int b = 0; b < 2 * BINS; ++b) red[wave][b] = acc[b];
    }
    __syncthreads();
    if (tid == 0) {
        float cum_c[BINS], cum_g[BINS];
        #pragma unroll
        for (int b = 0; b < BINS; ++b) { cum_c[b] = 0.0f; cum_g[b] = 0.0f; }
        for (int wv = 0; wv < 16; ++wv) {
            #pragma unroll
            for (int b = 0; b < BINS; ++b) {
                cum_c[b] += red[wv][b];
                cum_g[b] += red[wv][BINS + b];
            }
        }
        float nn = 0.0f, res = 0.0f;
        #pragma unroll
        for (int b = 0; b < BINS; ++b) {
            float Cb = (b < BINS - 1) ? (cum_c[b] - cum_c[b + 1]) : cum_c[b];
            float Sb = (b < BINS - 1) ? (cum_g[b] - cum_g[b + 1]) : cum_g[b];
            if (Cb > 0.5f) { nn += 1.0f; res += Sb / Cb; }
        }
        res *= 0.69314718f;         // ln2: G was accumulated in log2 units
        if (nn > 0.0f) res /= nn;   // total_num cancels exactly
        out[0] = res;
    }
}

extern "C" void kernel_launch(void* const* d_in, const int* in_sizes, int n_in,
                              void* d_out, int out_size, void* d_ws, size_t ws_size,
                              hipStream_t stream) {
    const int*   labels  = (const int*)d_in[0];
    const float* logits  = (const float*)d_in[1];
    const float* weights = (const float*)d_in[2];
    float* out     = (float*)d_out;
    float* partial = (float*)d_ws;

    const int n  = in_sizes[0];
    const int n4 = n / 4;

    int nb = 1440;                     // T=368,640 -> nfull=16 for this shape
    const size_t row_bytes = 2 * BINS * sizeof(float);
    if (ws_size < row_bytes * 1440) nb = 720;
    if (ws_size < row_bytes * 720)  nb = 360;

    ghm_partial<<<nb, K1_THREADS, 0, stream>>>(labels, logits, weights, partial,
                                               n4, n, nb);
    ghm_final<<<1, 1024, 0, stream>>>(partial, out, nb);
}